// Round 1
// baseline (258.651 us; speedup 1.0000x reference)
//
#include <hip/hip_runtime.h>
#include <hip/hip_bf16.h>
#include <math.h>

#define NB 512
#define TT 26
#define LL 64
#define HH 32
#define WW 128

__device__ __forceinline__ float wave_sum(float v) {
#pragma unroll
  for (int o = 32; o > 0; o >>= 1) v += __shfl_xor(v, o, 64);
  return v;
}

// ---------------- Phase 1: per-sample attention work ----------------
// grid = 512 blocks, 128 threads (one thread per output column w of interp)
__global__ __launch_bounds__(128) void k_phase1(
    const float* __restrict__ seq, const int* __restrict__ length,
    const float* __restrict__ alpha_p, float* __restrict__ wsA,
    unsigned long long* __restrict__ amid, unsigned int* __restrict__ alow,
    float* __restrict__ irr_sum)
{
  int b = blockIdx.x;
  int tid = threadIdx.x;
  __shared__ float att[LL * TT];   // att[l*26 + t] = seq[b, l, t]
  __shared__ float wpart[2];
  const float* sb = seq + (size_t)b * (LL * TT);
  for (int i = tid; i < LL * TT; i += 128) att[i] = sb[i];
  __syncthreads();
  int n = length[b] - 1;           // valid rows, in [1,26]
  float alpha = alpha_p[0];

  // interp column w: linear resize 64 -> 128, half-pixel, clamped
  int w = tid;
  int k = w >> 1;
  int i0, i1; float c0, c1;
  if ((w & 1) == 0) {
    if (k == 0) { i0 = 0; i1 = 0; c0 = 1.f; c1 = 0.f; }
    else        { i0 = k - 1; i1 = k; c0 = 0.25f; c1 = 0.75f; }
  } else {
    if (k == 63) { i0 = 63; i1 = 63; c0 = 1.f; c1 = 0.f; }
    else         { i0 = k; i1 = k + 1; c0 = 0.75f; c1 = 0.25f; }
  }
  float S = 0.f, S2 = 0.f, A = 0.f;
  for (int t = 0; t < n; ++t) {
    float v = c0 * att[i0 * TT + t] + c1 * att[i1 * TT + t];
    float s = v * v;
    S += s; S2 += s * s;
    A += 1.f / (1.f + expf(-70.f * (v - 0.1f)));
  }
  wsA[b * WW + w] = A;

  float c = S * S - S2;
  c = wave_sum(c);
  if ((tid & 63) == 0) wpart[tid >> 6] = c;
  __syncthreads();
  if (tid == 0) atomicAdd(irr_sum, 0.5f * (wpart[0] + wpart[1]) / (float)n);

  // packed attention-threshold bitmasks (row_valid already folded in: t>=n -> 0)
  if (tid < 64) {
    int x = tid;                       // middle: identity resize, 64 cols
    for (int t = 0; t < TT; ++t) {
      bool pred = (t < n) && (att[x * TT + t] > alpha);
      unsigned long long m = __ballot(pred);
      if (x == 0) amid[b * TT + t] = m;
    }
  } else {
    int x = tid - 64;                  // low: pairwise mean, 32 cols
    for (int t = 0; t < TT; ++t) {
      bool pred = (x < 32) && (t < n) &&
                  (0.5f * (att[(2 * x) * TT + t] + att[(2 * x + 1) * TT + t]) > alpha);
      unsigned long long m = __ballot(pred);
      if (x == 0) alow[b * TT + t] = (unsigned int)m;
    }
  }
}

// ---------------- Phase 2: seg CE + correct CE + fore bitmask ----------------
// grid = 2097152/256 blocks; each block entirely within one b
__global__ __launch_bounds__(256) void k_phase2(
    const float* __restrict__ masks, const float* __restrict__ bf,
    const float* __restrict__ wsA, float* __restrict__ seg_b,
    float* __restrict__ corr_sum, unsigned long long* __restrict__ fmsk)
{
  int idx = blockIdx.x * 256 + threadIdx.x;
  int b = idx >> 12;
  int rem = idx & 4095;
  int w = idx & 127;
  float m = masks[idx];
  float b0 = bf[(size_t)b * 8192 + rem];
  float b1 = bf[(size_t)b * 8192 + 4096 + rem];
  // softmax over 2 channels
  float mx = fmaxf(b0, b1);
  float e0 = expf(b0 - mx), e1 = expf(b1 - mx);
  float inv = 1.f / (e0 + e1);
  float p0 = e0 * inv, p1 = e1 * inv;
  int lab = m > 0.5f;
  // CE of (p0,p1) treated as logits
  float pm = fmaxf(p0, p1);
  float lse = pm + log1pf(expf(-fabsf(p1 - p0)));
  float ce_seg = lse - (lab ? p1 : p0);

  bool fore = b1 > b0;   // p1 > 0.5
  unsigned long long fb = __ballot(fore);
  if ((threadIdx.x & 63) == 0) fmsk[idx >> 6] = fb;

  float ce_c;
  if (fore) {
    float Av = wsA[b * WW + w];
    float cs = fminf(fmaxf(Av, 0.f), 1.f);
    ce_c = log1pf(expf(1.f - 2.f * cs));     // softplus(1-2c)
  } else {
    ce_c = 0.313261687518222834f;            // softplus(-1)
  }

  __shared__ float p_seg[4], p_cor[4];
  float rs = wave_sum(ce_seg);
  float rc = wave_sum(ce_c);
  int lane = threadIdx.x & 63, wv = threadIdx.x >> 6;
  if (lane == 0) { p_seg[wv] = rs; p_cor[wv] = rc; }
  __syncthreads();
  if (threadIdx.x == 0) {
    atomicAdd(&seg_b[b], p_seg[0] + p_seg[1] + p_seg[2] + p_seg[3]);
    atomicAdd(corr_sum, p_cor[0] + p_cor[1] + p_cor[2] + p_cor[3]);
  }
}

// ---------------- Phase 3a: middle char branch (16x64) ----------------
// grid = 512*4 blocks, 256 threads; block (b, quarter)
__global__ __launch_bounds__(256) void k_mid(
    const float* __restrict__ cm, const unsigned long long* __restrict__ fmsk,
    const unsigned long long* __restrict__ amid, float* __restrict__ out_soft,
    float* __restrict__ cel_acc, float* __restrict__ inter,
    float* __restrict__ m1s, float* __restrict__ m2s)
{
  int blk = blockIdx.x;
  int b = blk >> 2;
  int px = (blk & 3) * 256 + threadIdx.x;   // 0..1023
  int y = px >> 6, x = px & 63;
  __shared__ unsigned long long s_amid[TT];
  __shared__ float p_ce[4];
  if (threadIdx.x < TT) s_amid[threadIdx.x] = amid[b * TT + threadIdx.x];
  __syncthreads();

  // fm: 2x2 block mean >= 0.4  <=>  count >= 2
  int h0 = 2 * y, wb = 2 * x;
  int word = wb >> 6, bit = wb & 63;
  unsigned long long r0 = fmsk[((size_t)b * HH + h0) * 2 + word];
  unsigned long long r1 = fmsk[((size_t)b * HH + h0 + 1) * 2 + word];
  int cnt = (int)((r0 >> bit) & 1) + (int)((r0 >> (bit + 1)) & 1)
          + (int)((r1 >> bit) & 1) + (int)((r1 >> (bit + 1)) & 1);
  bool fm = cnt >= 2;
  int label = 0;
  if (fm) {
#pragma unroll 1
    for (int t = 0; t < TT; ++t) {
      if ((s_amid[t] >> x) & 1ULL) { label = t + 1; break; }
    }
  }

  const float* base = cm + (size_t)b * 27 * 1024 + px;
  float v[27]; float mx = -1e30f; float xl = 0.f;
#pragma unroll
  for (int c = 0; c < 27; ++c) { v[c] = base[(size_t)c * 1024]; mx = fmaxf(mx, v[c]); }
#pragma unroll
  for (int c = 0; c < 27; ++c) { if (c == label) xl = v[c]; }
  float s = 0.f;
#pragma unroll
  for (int c = 0; c < 27; ++c) { v[c] = expf(v[c] - mx); s += v[c]; }
  float invs = 1.f / s;
  float ce = mx + logf(s) - xl;

  float* os = out_soft + (size_t)b * 26 * 1024 + px;
  int lane = threadIdx.x & 63;
#pragma unroll 1
  for (int t = 0; t < 26; ++t) {
    float m1 = v[t + 1] * invs;
    os[(size_t)t * 1024] = m1;
    bool m2 = fm && ((s_amid[t] >> x) & 1ULL);
    float r_m1 = wave_sum(m1);
    float r_in = wave_sum(m2 ? m1 : 0.f);
    unsigned long long bm = __ballot(m2);
    if (lane == 0) {
      atomicAdd(&m1s[b * 26 + t], r_m1);
      atomicAdd(&inter[b * 26 + t], r_in);
      atomicAdd(&m2s[b * 26 + t], (float)__popcll(bm));
    }
  }
  float rce = wave_sum(ce);
  if (lane == 0) p_ce[threadIdx.x >> 6] = rce;
  __syncthreads();
  if (threadIdx.x == 0) atomicAdd(cel_acc, p_ce[0] + p_ce[1] + p_ce[2] + p_ce[3]);
}

// ---------------- Phase 3b: low char branch (8x32) + mask27 output ----------------
// grid = 512 blocks, 256 threads (one block per b)
__global__ __launch_bounds__(256) void k_low(
    const float* __restrict__ cl, const unsigned long long* __restrict__ fmsk,
    const unsigned int* __restrict__ alow, float* __restrict__ out_mask,
    float* __restrict__ out_soft, float* __restrict__ cel_acc,
    float* __restrict__ inter, float* __restrict__ m1s, float* __restrict__ m2s)
{
  int b = blockIdx.x;
  int px = threadIdx.x;
  int y = px >> 5, x = px & 31;
  __shared__ unsigned int s_alow[TT];
  __shared__ float p_ce[4];
  if (threadIdx.x < TT) s_alow[threadIdx.x] = alow[b * TT + threadIdx.x];
  __syncthreads();

  // fm: mean of rows 4y+1,4y+2 cols 4x+1,4x+2 >= 0.4 <=> count >= 2
  int wb = 4 * x + 1;
  int word = wb >> 6, bit = wb & 63;
  unsigned long long r0 = fmsk[((size_t)b * HH + 4 * y + 1) * 2 + word];
  unsigned long long r1 = fmsk[((size_t)b * HH + 4 * y + 2) * 2 + word];
  int cnt = (int)((r0 >> bit) & 1) + (int)((r0 >> (bit + 1)) & 1)
          + (int)((r1 >> bit) & 1) + (int)((r1 >> (bit + 1)) & 1);
  bool fm = cnt >= 2;
  int label = 0;
  if (fm) {
#pragma unroll 1
    for (int t = 0; t < TT; ++t) {
      if ((s_alow[t] >> x) & 1u) { label = t + 1; break; }
    }
  }

  const float* base = cl + (size_t)b * 27 * 256 + px;
  float v[27]; float mx = -1e30f; float xl = 0.f;
#pragma unroll
  for (int c = 0; c < 27; ++c) { v[c] = base[(size_t)c * 256]; mx = fmaxf(mx, v[c]); }
#pragma unroll
  for (int c = 0; c < 27; ++c) { if (c == label) xl = v[c]; }
  float s = 0.f;
#pragma unroll
  for (int c = 0; c < 27; ++c) { v[c] = expf(v[c] - mx); s += v[c]; }
  float invs = 1.f / s;
  float ce = mx + logf(s) - xl;

  float* om = out_mask + (size_t)b * 27 * 256 + px;
  om[0] = fm ? 0.f : 1.f;
  float* osf = out_soft + (size_t)b * 26 * 256 + px;
  int lane = threadIdx.x & 63;
#pragma unroll 1
  for (int t = 0; t < 26; ++t) {
    bool m2 = fm && ((s_alow[t] >> x) & 1u);
    om[(size_t)(t + 1) * 256] = m2 ? 1.f : 0.f;
    float m1 = v[t + 1] * invs;
    osf[(size_t)t * 256] = m1;
    float r_m1 = wave_sum(m1);
    float r_in = wave_sum(m2 ? m1 : 0.f);
    unsigned long long bm = __ballot(m2);
    if (lane == 0) {
      atomicAdd(&m1s[b * 26 + t], r_m1);
      atomicAdd(&inter[b * 26 + t], r_in);
      atomicAdd(&m2s[b * 26 + t], (float)__popcll(bm));
    }
  }
  float rce = wave_sum(ce);
  if (lane == 0) p_ce[threadIdx.x >> 6] = rce;
  __syncthreads();
  if (threadIdx.x == 0) atomicAdd(cel_acc, p_ce[0] + p_ce[1] + p_ce[2] + p_ce[3]);
}

// ---------------- Phase 4: finalize scalars ----------------
__global__ __launch_bounds__(256) void k_final(
    const float* __restrict__ acc,   // [0]=corr_sum [1]=irr [2]=cel_mid [3]=cel_low
    const float* __restrict__ seg_b,
    const float* __restrict__ inter_mid, const float* __restrict__ m1s_mid,
    const float* __restrict__ m2s_mid,
    const float* __restrict__ inter_low, const float* __restrict__ m1s_low,
    const float* __restrict__ m2s_low,
    const int* __restrict__ length, const int* __restrict__ iter_p,
    float* __restrict__ out)
{
  int tid = threadIdx.x;
  float dm = 0.f, dl = 0.f;
  for (int i = tid; i < NB * 26; i += 256) {
    int b = i / 26, t = i % 26;
    int n = length[b] - 1;
    if (t < n) {
      float inv_n = 1.f / (float)n;
      float sc_m = (2.f * inter_mid[i] + 1.f) / (m1s_mid[i] + m2s_mid[i] + 1.f);
      dm += (1.f - sc_m) * inv_n;
      float sc_l = (2.f * inter_low[i] + 1.f) / (m1s_low[i] + m2s_low[i] + 1.f);
      dl += (1.f - sc_l) * inv_n;
    }
  }
  float ss = 0.f, sel = 0.f, ssel = 0.f;
  for (int b = tid; b < NB; b += 256) {
    float v = seg_b[b];
    ss += v;
    float val = v * (1.f / 4096.f);
    if (val < 1.f) { sel += 1.f; ssel += val; }
  }
  __shared__ float p[5][4];
  dm = wave_sum(dm); dl = wave_sum(dl); ss = wave_sum(ss);
  sel = wave_sum(sel); ssel = wave_sum(ssel);
  int lane = tid & 63, wv = tid >> 6;
  if (lane == 0) { p[0][wv] = dm; p[1][wv] = dl; p[2][wv] = ss; p[3][wv] = sel; p[4][wv] = ssel; }
  __syncthreads();
  if (tid == 0) {
    float DM = 0, DL = 0, SS = 0, SEL = 0, SSEL = 0;
    for (int i = 0; i < 4; ++i) {
      DM += p[0][i]; DL += p[1][i]; SS += p[2][i]; SEL += p[3][i]; SSEL += p[4][i];
    }
    float pred;
    if (iter_p[0] > 20000) pred = SSEL / fmaxf(SEL, 1.f);
    else pred = SS / 2097152.f;
    out[0] = pred;
    out[1] = acc[0] / 2097152.f + acc[1];
    out[2] = acc[3] / 131072.f + DL / 512.f;   // loss_low
    out[3] = acc[2] / 524288.f + DM / 512.f;   // loss_middle
  }
}

extern "C" void kernel_launch(void* const* d_in, const int* in_sizes, int n_in,
                              void* d_out, int out_size, void* d_ws, size_t ws_size,
                              hipStream_t stream) {
  (void)in_sizes; (void)n_in; (void)out_size; (void)ws_size;
  const float* masks  = (const float*)d_in[0];
  const float* bf     = (const float*)d_in[1];
  const float* seq    = (const float*)d_in[2];
  const float* cmid   = (const float*)d_in[3];
  const float* clow   = (const float*)d_in[4];
  const int*   length = (const int*)d_in[5];
  const int*   iter   = (const int*)d_in[6];
  const float* alpha  = (const float*)d_in[7];
  float* out = (float*)d_out;

  char* ws = (char*)d_ws;
  // accumulators (zeroed each launch): bytes [0, 321552)
  float* acc       = (float*)(ws + 0);        // 4 scalars
  float* seg_b     = (float*)(ws + 16);       // 512 f32
  float* inter_mid = (float*)(ws + 2064);     // 13312 f32
  float* m1s_mid   = (float*)(ws + 55312);
  float* m2s_mid   = (float*)(ws + 108560);
  float* inter_low = (float*)(ws + 161808);
  float* m1s_low   = (float*)(ws + 215056);
  float* m2s_low   = (float*)(ws + 268304);
  // non-accumulated scratch (fully rewritten each launch)
  unsigned long long* amid = (unsigned long long*)(ws + 321552);  // 512*26 u64
  unsigned int*       alow = (unsigned int*)(ws + 428048);        // 512*26 u32
  unsigned long long* fmsk = (unsigned long long*)(ws + 481296);  // 512*32*2 u64
  float*              wsA  = (float*)(ws + 743440);               // 512*128 f32

  hipMemsetAsync(d_ws, 0, 321552, stream);

  k_phase1<<<NB, 128, 0, stream>>>(seq, length, alpha, wsA, amid, alow, acc + 1);
  k_phase2<<<(NB * HH * WW) / 256, 256, 0, stream>>>(masks, bf, wsA, seg_b, acc + 0, fmsk);

  float* out_mask = out + 4;
  float* out_smid = out + 4 + 3538944;
  float* out_slow = out + 4 + 3538944 + 13631488;

  k_mid<<<NB * 4, 256, 0, stream>>>(cmid, fmsk, amid, out_smid, acc + 2,
                                    inter_mid, m1s_mid, m2s_mid);
  k_low<<<NB, 256, 0, stream>>>(clow, fmsk, alow, out_mask, out_slow, acc + 3,
                                inter_low, m1s_low, m2s_low);
  k_final<<<1, 256, 0, stream>>>(acc, seg_b, inter_mid, m1s_mid, m2s_mid,
                                 inter_low, m1s_low, m2s_low, length, iter, out);
}

// Round 2
// 136.803 us; speedup vs baseline: 1.8907x; 1.8907x over previous
//
#include <hip/hip_runtime.h>
#include <hip/hip_bf16.h>
#include <math.h>

#define NB 512
#define TT 26
#define LL 64
#define HH 32
#define WW 128

typedef unsigned long long ull;

__device__ __forceinline__ float wave_sum(float v) {
#pragma unroll
  for (int o = 32; o > 0; o >>= 1) v += __shfl_xor(v, o, 64);
  return v;
}

// parts layout (f32): [0..63]=irr, [64..127]=cor, [128..191]=cel_mid, [192..255]=cel_low

// ---------------- Phase 1: per-sample attention work ----------------
__global__ __launch_bounds__(128) void k_phase1(
    const float* __restrict__ seq, const int* __restrict__ length,
    const float* __restrict__ alpha_p, float* __restrict__ wsA,
    ull* __restrict__ amid, unsigned int* __restrict__ alow,
    float* __restrict__ parts)
{
  int b = blockIdx.x;
  int tid = threadIdx.x;
  __shared__ float att[LL * TT];
  __shared__ float wpart[2];
  const float* sb = seq + (size_t)b * (LL * TT);
  for (int i = tid; i < LL * TT; i += 128) att[i] = sb[i];
  __syncthreads();
  int n = length[b] - 1;
  float alpha = alpha_p[0];

  // interp column w: linear resize 64 -> 128, half-pixel, clamped
  int w = tid;
  int k = w >> 1;
  int i0, i1; float c0, c1;
  if ((w & 1) == 0) {
    if (k == 0) { i0 = 0; i1 = 0; c0 = 1.f; c1 = 0.f; }
    else        { i0 = k - 1; i1 = k; c0 = 0.25f; c1 = 0.75f; }
  } else {
    if (k == 63) { i0 = 63; i1 = 63; c0 = 1.f; c1 = 0.f; }
    else         { i0 = k; i1 = k + 1; c0 = 0.75f; c1 = 0.25f; }
  }
  float S = 0.f, S2 = 0.f, A = 0.f;
  for (int t = 0; t < n; ++t) {
    float v = c0 * att[i0 * TT + t] + c1 * att[i1 * TT + t];
    float s = v * v;
    S += s; S2 += s * s;
    A += 1.f / (1.f + expf(-70.f * (v - 0.1f)));
  }
  wsA[b * WW + w] = A;

  float c = S * S - S2;
  c = wave_sum(c);
  if ((tid & 63) == 0) wpart[tid >> 6] = c;
  __syncthreads();
  if (tid == 0) atomicAdd(&parts[b & 63], 0.5f * (wpart[0] + wpart[1]) / (float)n);

  if (tid < 64) {
    int x = tid;                       // middle: identity resize, 64 cols
    for (int t = 0; t < TT; ++t) {
      bool pred = (t < n) && (att[x * TT + t] > alpha);
      ull m = __ballot(pred);
      if (x == 0) amid[b * TT + t] = m;
    }
  } else {
    int x = tid - 64;                  // low: pairwise mean, 32 cols
    for (int t = 0; t < TT; ++t) {
      bool pred = (x < 32) && (t < n) &&
                  (0.5f * (att[(2 * x) * TT + t] + att[(2 * x + 1) * TT + t]) > alpha);
      ull m = __ballot(pred);
      if (x == 0) alow[b * TT + t] = (unsigned int)m;
    }
  }
}

// ---------------- Phase 2: seg CE + correct CE + fore bitmask ----------------
__global__ __launch_bounds__(256) void k_phase2(
    const float* __restrict__ masks, const float* __restrict__ bf,
    const float* __restrict__ wsA, float* __restrict__ seg_b,
    float* __restrict__ parts, ull* __restrict__ fmsk)
{
  int idx = blockIdx.x * 256 + threadIdx.x;
  int b = idx >> 12;
  int rem = idx & 4095;
  int w = idx & 127;
  float m = masks[idx];
  float b0 = bf[(size_t)b * 8192 + rem];
  float b1 = bf[(size_t)b * 8192 + 4096 + rem];
  float mx = fmaxf(b0, b1);
  float e0 = expf(b0 - mx), e1 = expf(b1 - mx);
  float inv = 1.f / (e0 + e1);
  float p0 = e0 * inv, p1 = e1 * inv;
  int lab = m > 0.5f;
  float pm = fmaxf(p0, p1);
  float lse = pm + log1pf(expf(-fabsf(p1 - p0)));
  float ce_seg = lse - (lab ? p1 : p0);

  bool fore = b1 > b0;
  ull fb = __ballot(fore);
  if ((threadIdx.x & 63) == 0) fmsk[idx >> 6] = fb;

  float ce_c;
  if (fore) {
    float Av = wsA[b * WW + w];
    float cs = fminf(fmaxf(Av, 0.f), 1.f);
    ce_c = log1pf(expf(1.f - 2.f * cs));
  } else {
    ce_c = 0.313261687518222834f;
  }

  __shared__ float p_seg[4], p_cor[4];
  float rs = wave_sum(ce_seg);
  float rc = wave_sum(ce_c);
  int lane = threadIdx.x & 63, wv = threadIdx.x >> 6;
  if (lane == 0) { p_seg[wv] = rs; p_cor[wv] = rc; }
  __syncthreads();
  if (threadIdx.x == 0) {
    atomicAdd(&seg_b[b], p_seg[0] + p_seg[1] + p_seg[2] + p_seg[3]);
    atomicAdd(&parts[64 + (blockIdx.x & 63)], p_cor[0] + p_cor[1] + p_cor[2] + p_cor[3]);
  }
}

// ---------------- Phase 3 (fused): low blocks [0,NB), mid blocks [NB, NB+4*NB) ----------------
__global__ __launch_bounds__(256) void k_chars(
    const float* __restrict__ cm, const float* __restrict__ cl,
    const ull* __restrict__ fmsk, const ull* __restrict__ amid,
    const unsigned int* __restrict__ alow,
    float* __restrict__ out_mask, float* __restrict__ out_smid,
    float* __restrict__ out_slow, float* __restrict__ parts,
    float* __restrict__ inter_mid, float* __restrict__ m1s_mid, float* __restrict__ m2s_mid,
    float* __restrict__ inter_low, float* __restrict__ m1s_low, float* __restrict__ m2s_low)
{
  int blk = blockIdx.x;
  int tid = threadIdx.x;
  int lane = tid & 63, wv = tid >> 6;
  __shared__ float part[4][80];     // [wave][0..25]=inter, [26..51]=m1s, [52..77]=m2s, [78]=ce
  __shared__ ull s_bits[TT];

  if (blk < NB) {
    // ---------- low branch (8x32) ----------
    int b = blk;
    int px = tid, y = px >> 5, x = px & 31;
    if (tid < TT) s_bits[tid] = alow[b * TT + tid];
    __syncthreads();
    int wb = 4 * x + 1;
    int word = wb >> 6, bit = wb & 63;
    ull r0 = fmsk[((size_t)b * HH + 4 * y + 1) * 2 + word];
    ull r1 = fmsk[((size_t)b * HH + 4 * y + 2) * 2 + word];
    int cnt = (int)((r0 >> bit) & 1) + (int)((r0 >> (bit + 1)) & 1)
            + (int)((r1 >> bit) & 1) + (int)((r1 >> (bit + 1)) & 1);
    bool fm = cnt >= 2;
    int label = 0;
    if (fm) {
#pragma unroll 1
      for (int t = 0; t < TT; ++t) {
        if ((s_bits[t] >> x) & 1ULL) { label = t + 1; break; }
      }
    }
    const float* base = cl + (size_t)b * 27 * 256 + px;
    float v[27]; float mx = -1e30f; float xl = 0.f;
#pragma unroll
    for (int c = 0; c < 27; ++c) { v[c] = base[(size_t)c * 256]; mx = fmaxf(mx, v[c]); }
#pragma unroll
    for (int c = 0; c < 27; ++c) { if (c == label) xl = v[c]; }
    float s = 0.f;
#pragma unroll
    for (int c = 0; c < 27; ++c) { v[c] = expf(v[c] - mx); s += v[c]; }
    float invs = 1.f / s;
    float ce = mx + logf(s) - xl;

    float* om = out_mask + (size_t)b * 27 * 256 + px;
    om[0] = fm ? 0.f : 1.f;
    float* osf = out_slow + (size_t)b * 26 * 256 + px;
#pragma unroll 1
    for (int t = 0; t < TT; ++t) {
      bool m2 = fm && ((s_bits[t] >> x) & 1ULL);
      om[(size_t)(t + 1) * 256] = m2 ? 1.f : 0.f;
      float m1 = v[t + 1] * invs;
      osf[(size_t)t * 256] = m1;
      float r_in = wave_sum(m2 ? m1 : 0.f);
      float r_m1 = wave_sum(m1);
      ull bm = __ballot(m2);
      if (lane == 0) {
        part[wv][t] = r_in; part[wv][26 + t] = r_m1; part[wv][52 + t] = (float)__popcll(bm);
      }
    }
    float rce = wave_sum(ce);
    if (lane == 0) part[wv][78] = rce;
    __syncthreads();
    if (tid < 78) {
      float sm = part[0][tid] + part[1][tid] + part[2][tid] + part[3][tid];
      int q = tid / 26, t = tid - q * 26;
      float* dst = (q == 0) ? inter_low : ((q == 1) ? m1s_low : m2s_low);
      dst[b * TT + t] = sm;   // single block per b -> direct store
    }
    if (tid == 0)
      atomicAdd(&parts[192 + (b & 63)], part[0][78] + part[1][78] + part[2][78] + part[3][78]);
  } else {
    // ---------- mid branch (16x64), 4 blocks per b ----------
    int bm_ = blk - NB;
    int b = bm_ >> 2;
    int px = (bm_ & 3) * 256 + tid;    // 0..1023
    int y = px >> 6, x = px & 63;
    if (tid < TT) s_bits[tid] = amid[b * TT + tid];
    __syncthreads();
    int h0 = 2 * y, wb = 2 * x;
    int word = wb >> 6, bit = wb & 63;
    ull r0 = fmsk[((size_t)b * HH + h0) * 2 + word];
    ull r1 = fmsk[((size_t)b * HH + h0 + 1) * 2 + word];
    int cnt = (int)((r0 >> bit) & 1) + (int)((r0 >> (bit + 1)) & 1)
            + (int)((r1 >> bit) & 1) + (int)((r1 >> (bit + 1)) & 1);
    bool fm = cnt >= 2;
    int label = 0;
    if (fm) {
#pragma unroll 1
      for (int t = 0; t < TT; ++t) {
        if ((s_bits[t] >> x) & 1ULL) { label = t + 1; break; }
      }
    }
    const float* base = cm + (size_t)b * 27 * 1024 + px;
    float v[27]; float mx = -1e30f; float xl = 0.f;
#pragma unroll
    for (int c = 0; c < 27; ++c) { v[c] = base[(size_t)c * 1024]; mx = fmaxf(mx, v[c]); }
#pragma unroll
    for (int c = 0; c < 27; ++c) { if (c == label) xl = v[c]; }
    float s = 0.f;
#pragma unroll
    for (int c = 0; c < 27; ++c) { v[c] = expf(v[c] - mx); s += v[c]; }
    float invs = 1.f / s;
    float ce = mx + logf(s) - xl;

    float* os = out_smid + (size_t)b * 26 * 1024 + px;
#pragma unroll 1
    for (int t = 0; t < TT; ++t) {
      float m1 = v[t + 1] * invs;
      os[(size_t)t * 1024] = m1;
      bool m2 = fm && ((s_bits[t] >> x) & 1ULL);
      float r_in = wave_sum(m2 ? m1 : 0.f);
      float r_m1 = wave_sum(m1);
      ull bm = __ballot(m2);
      if (lane == 0) {
        part[wv][t] = r_in; part[wv][26 + t] = r_m1; part[wv][52 + t] = (float)__popcll(bm);
      }
    }
    float rce = wave_sum(ce);
    if (lane == 0) part[wv][78] = rce;
    __syncthreads();
    if (tid < 78) {
      float sm = part[0][tid] + part[1][tid] + part[2][tid] + part[3][tid];
      int q = tid / 26, t = tid - q * 26;
      float* dst = (q == 0) ? inter_mid : ((q == 1) ? m1s_mid : m2s_mid);
      atomicAdd(&dst[b * TT + t], sm);   // 4 contenders per address
    }
    if (tid == 0)
      atomicAdd(&parts[128 + (blk & 63)], part[0][78] + part[1][78] + part[2][78] + part[3][78]);
  }
}

// ---------------- Phase 4: finalize scalars ----------------
__global__ __launch_bounds__(1024) void k_final(
    const float* __restrict__ parts, const float* __restrict__ seg_b,
    const float* __restrict__ inter_mid, const float* __restrict__ m1s_mid,
    const float* __restrict__ m2s_mid,
    const float* __restrict__ inter_low, const float* __restrict__ m1s_low,
    const float* __restrict__ m2s_low,
    const int* __restrict__ length, const int* __restrict__ iter_p,
    float* __restrict__ out)
{
  int tid = threadIdx.x;
  float dm = 0.f, dl = 0.f;
  for (int i = tid; i < NB * TT; i += 1024) {
    int b = i / TT, t = i - b * TT;
    int n = length[b] - 1;
    if (t < n) {
      float inv_n = 1.f / (float)n;
      dm += (1.f - (2.f * inter_mid[i] + 1.f) / (m1s_mid[i] + m2s_mid[i] + 1.f)) * inv_n;
      dl += (1.f - (2.f * inter_low[i] + 1.f) / (m1s_low[i] + m2s_low[i] + 1.f)) * inv_n;
    }
  }
  float ss = 0.f, sel = 0.f, ssel = 0.f;
  for (int b = tid; b < NB; b += 1024) {
    float v = seg_b[b];
    ss += v;
    float val = v * (1.f / 4096.f);
    if (val < 1.f) { sel += 1.f; ssel += val; }
  }
  float pv = (tid < 256) ? parts[tid] : 0.f;   // wave 0:irr 1:cor 2:celm 3:cell
  dm = wave_sum(dm); dl = wave_sum(dl); ss = wave_sum(ss);
  sel = wave_sum(sel); ssel = wave_sum(ssel); pv = wave_sum(pv);
  __shared__ float red[6][16];
  int wv = tid >> 6;
  if ((tid & 63) == 0) {
    red[0][wv] = dm; red[1][wv] = dl; red[2][wv] = ss;
    red[3][wv] = sel; red[4][wv] = ssel; red[5][wv] = pv;
  }
  __syncthreads();
  if (tid == 0) {
    float DM = 0, DL = 0, SS = 0, SEL = 0, SSEL = 0;
    for (int i = 0; i < 16; ++i) {
      DM += red[0][i]; DL += red[1][i]; SS += red[2][i];
      SEL += red[3][i]; SSEL += red[4][i];
    }
    float IRR = red[5][0], COR = red[5][1], CELM = red[5][2], CELL = red[5][3];
    float pred = (iter_p[0] > 20000) ? (SSEL / fmaxf(SEL, 1.f)) : (SS / 2097152.f);
    out[0] = pred;
    out[1] = COR / 2097152.f + IRR;
    out[2] = CELL / 131072.f + DL / 512.f;   // loss_low
    out[3] = CELM / 524288.f + DM / 512.f;   // loss_middle
  }
}

extern "C" void kernel_launch(void* const* d_in, const int* in_sizes, int n_in,
                              void* d_out, int out_size, void* d_ws, size_t ws_size,
                              hipStream_t stream) {
  (void)in_sizes; (void)n_in; (void)out_size; (void)ws_size;
  const float* masks  = (const float*)d_in[0];
  const float* bf     = (const float*)d_in[1];
  const float* seq    = (const float*)d_in[2];
  const float* cmid   = (const float*)d_in[3];
  const float* clow   = (const float*)d_in[4];
  const int*   length = (const int*)d_in[5];
  const int*   iter   = (const int*)d_in[6];
  const float* alpha  = (const float*)d_in[7];
  float* out = (float*)d_out;

  char* ws = (char*)d_ws;
  // zeroed region [0, 162816)
  float* parts     = (float*)(ws + 0);        // 256 f32 scalar-part slots
  float* seg_b     = (float*)(ws + 1024);     // 512 f32
  float* inter_mid = (float*)(ws + 3072);     // 13312 f32 each
  float* m1s_mid   = (float*)(ws + 56320);
  float* m2s_mid   = (float*)(ws + 109568);
  // non-accumulated scratch (fully rewritten every launch)
  ull*          amid = (ull*)(ws + 162816);          // 512*26 u64
  unsigned int* alow = (unsigned int*)(ws + 269312); // 512*26 u32
  ull*          fmsk = (ull*)(ws + 322560);          // 512*32*2 u64
  float*        wsA  = (float*)(ws + 584704);        // 512*128 f32 (dead after k_phase2)
  // low dice arrays alias wsA region (written by k_chars, after wsA's last read)
  float* inter_low = (float*)(ws + 584704);
  float* m1s_low   = (float*)(ws + 637952);
  float* m2s_low   = (float*)(ws + 691200);          // ends 744448

  hipMemsetAsync(d_ws, 0, 162816, stream);

  k_phase1<<<NB, 128, 0, stream>>>(seq, length, alpha, wsA, amid, alow, parts);
  k_phase2<<<(NB * HH * WW) / 256, 256, 0, stream>>>(masks, bf, wsA, seg_b, parts, fmsk);

  float* out_mask = out + 4;
  float* out_smid = out + 4 + 3538944;
  float* out_slow = out + 4 + 3538944 + 13631488;

  k_chars<<<NB * 5, 256, 0, stream>>>(cmid, clow, fmsk, amid, alow,
                                      out_mask, out_smid, out_slow, parts,
                                      inter_mid, m1s_mid, m2s_mid,
                                      inter_low, m1s_low, m2s_low);
  k_final<<<1, 1024, 0, stream>>>(parts, seg_b, inter_mid, m1s_mid, m2s_mid,
                                  inter_low, m1s_low, m2s_low, length, iter, out);
}

// Round 3
// 117.230 us; speedup vs baseline: 2.2064x; 1.1670x over previous
//
#include <hip/hip_runtime.h>
#include <hip/hip_bf16.h>
#include <math.h>

#define NB 512
#define TT 26
#define LL 64
#define HH 32
#define WW 128

typedef unsigned long long ull;

__device__ __forceinline__ float wave_sum(float v) {
#pragma unroll
  for (int o = 32; o > 0; o >>= 1) v += __shfl_xor(v, o, 64);
  return v;
}

// parts layout (f32): [0..63]=irr, [64..127]=cor, [128..191]=cel_mid, [192..255]=cel_low

// ---------------- Phase 1: per-sample attention work ----------------
__global__ __launch_bounds__(128) void k_phase1(
    const float* __restrict__ seq, const int* __restrict__ length,
    const float* __restrict__ alpha_p, float* __restrict__ wsA,
    ull* __restrict__ amid, unsigned int* __restrict__ alow,
    float* __restrict__ parts)
{
  int b = blockIdx.x;
  int tid = threadIdx.x;
  __shared__ float att[LL * TT];
  __shared__ float wpart[2];
  const float* sb = seq + (size_t)b * (LL * TT);
  for (int i = tid; i < LL * TT; i += 128) att[i] = sb[i];
  __syncthreads();
  int n = length[b] - 1;
  float alpha = alpha_p[0];

  // interp column w: linear resize 64 -> 128, half-pixel, clamped
  int w = tid;
  int k = w >> 1;
  int i0, i1; float c0, c1;
  if ((w & 1) == 0) {
    if (k == 0) { i0 = 0; i1 = 0; c0 = 1.f; c1 = 0.f; }
    else        { i0 = k - 1; i1 = k; c0 = 0.25f; c1 = 0.75f; }
  } else {
    if (k == 63) { i0 = 63; i1 = 63; c0 = 1.f; c1 = 0.f; }
    else         { i0 = k; i1 = k + 1; c0 = 0.75f; c1 = 0.25f; }
  }
  float S = 0.f, S2 = 0.f, A = 0.f;
  for (int t = 0; t < n; ++t) {
    float v = c0 * att[i0 * TT + t] + c1 * att[i1 * TT + t];
    float s = v * v;
    S += s; S2 += s * s;
    A += 1.f / (1.f + __expf(-70.f * (v - 0.1f)));
  }
  wsA[b * WW + w] = A;

  float c = S * S - S2;
  c = wave_sum(c);
  if ((tid & 63) == 0) wpart[tid >> 6] = c;
  __syncthreads();
  if (tid == 0) atomicAdd(&parts[b & 63], 0.5f * (wpart[0] + wpart[1]) / (float)n);

  if (tid < 64) {
    int x = tid;                       // middle: identity resize, 64 cols
    for (int t = 0; t < TT; ++t) {
      bool pred = (t < n) && (att[x * TT + t] > alpha);
      ull m = __ballot(pred);
      if (x == 0) amid[b * TT + t] = m;
    }
  } else {
    int x = tid - 64;                  // low: pairwise mean, 32 cols
    for (int t = 0; t < TT; ++t) {
      bool pred = (x < 32) && (t < n) &&
                  (0.5f * (att[(2 * x) * TT + t] + att[(2 * x + 1) * TT + t]) > alpha);
      ull m = __ballot(pred);
      if (x == 0) alow[b * TT + t] = (unsigned int)m;
    }
  }
}

// ---------------- Phase 2: seg CE + correct CE + fore bitmask ----------------
__global__ __launch_bounds__(256) void k_phase2(
    const float* __restrict__ masks, const float* __restrict__ bf,
    const float* __restrict__ wsA, float* __restrict__ seg_b,
    float* __restrict__ parts, ull* __restrict__ fmsk)
{
  int idx = blockIdx.x * 256 + threadIdx.x;
  int b = idx >> 12;
  int rem = idx & 4095;
  int w = idx & 127;
  float m = masks[idx];
  float b0 = bf[(size_t)b * 8192 + rem];
  float b1 = bf[(size_t)b * 8192 + 4096 + rem];
  float mx = fmaxf(b0, b1);
  float e0 = __expf(b0 - mx), e1 = __expf(b1 - mx);
  float inv = 1.f / (e0 + e1);
  float p0 = e0 * inv, p1 = e1 * inv;
  int lab = m > 0.5f;
  float pm = fmaxf(p0, p1);
  float lse = pm + log1pf(__expf(-fabsf(p1 - p0)));
  float ce_seg = lse - (lab ? p1 : p0);

  bool fore = b1 > b0;
  ull fb = __ballot(fore);
  if ((threadIdx.x & 63) == 0) fmsk[idx >> 6] = fb;

  float ce_c;
  if (fore) {
    float Av = wsA[b * WW + w];
    float cs = fminf(fmaxf(Av, 0.f), 1.f);
    ce_c = log1pf(__expf(1.f - 2.f * cs));
  } else {
    ce_c = 0.313261687518222834f;
  }

  __shared__ float p_seg[4], p_cor[4];
  float rs = wave_sum(ce_seg);
  float rc = wave_sum(ce_c);
  int lane = threadIdx.x & 63, wv = threadIdx.x >> 6;
  if (lane == 0) { p_seg[wv] = rs; p_cor[wv] = rc; }
  __syncthreads();
  if (threadIdx.x == 0) {
    atomicAdd(&seg_b[b], p_seg[0] + p_seg[1] + p_seg[2] + p_seg[3]);
    atomicAdd(&parts[64 + (blockIdx.x & 63)], p_cor[0] + p_cor[1] + p_cor[2] + p_cor[3]);
  }
}

// ---------------- Phase 3 (fused, float4): mid blocks [0,NB), low blocks [NB, NB+NB/4) ----------------
__global__ __launch_bounds__(256) void k_chars(
    const float* __restrict__ cm, const float* __restrict__ cl,
    const ull* __restrict__ fmsk, const ull* __restrict__ amid,
    const unsigned int* __restrict__ alow,
    float* __restrict__ out_mask, float* __restrict__ out_smid,
    float* __restrict__ out_slow, float* __restrict__ parts,
    float* __restrict__ inter_mid, float* __restrict__ m1s_mid, float* __restrict__ m2s_mid,
    float* __restrict__ inter_low, float* __restrict__ m1s_low, float* __restrict__ m2s_low)
{
  int blk = blockIdx.x;
  int tid = threadIdx.x;
  int lane = tid & 63, wv = tid >> 6;

  if (blk < NB) {
    // ================= mid branch: one block per b, 4 px per thread =================
    int b = blk;
    __shared__ ull s_bits[TT];
    __shared__ unsigned s_cols[64];
    __shared__ ull s_fmrow[16];
    __shared__ float s_in[4][TT], s_m1[4][TT], s_ce[4];
    if (tid < TT) s_bits[tid] = amid[b * TT + tid];
    __syncthreads();
    if (tid < 64) {
      unsigned cb = 0;
#pragma unroll
      for (int t = 0; t < TT; ++t) cb |= (unsigned)((s_bits[t] >> tid) & 1ULL) << t;
      s_cols[tid] = cb;
    } else if (tid < 80) {
      s_fmrow[tid - 64] = 0ULL;
    }
    __syncthreads();

    int y = tid >> 4;            // 0..15
    int x0 = (tid & 15) * 4;     // 0..60, 4-aligned
    int word = x0 >> 5;
    ull r0 = fmsk[((size_t)b * HH + 2 * y) * 2 + word];
    ull r1 = fmsk[((size_t)b * HH + 2 * y + 1) * 2 + word];
    unsigned cbk[4]; int labk[4]; int fmn = 0;
#pragma unroll
    for (int k = 0; k < 4; ++k) {
      int p = (2 * (x0 + k)) & 63;
      int c = (int)((r0 >> p) & 1) + (int)((r0 >> (p + 1)) & 1)
            + (int)((r1 >> p) & 1) + (int)((r1 >> (p + 1)) & 1);
      bool fm = c >= 2;
      cbk[k] = s_cols[x0 + k];
      labk[k] = (fm && cbk[k]) ? __ffs((int)cbk[k]) : 0;  // label = t+1
      if (!fm) cbk[k] = 0;                                // fold fm into m2 bits
      if (fm) fmn |= 1 << k;
    }
    if (fmn) atomicOr(&s_fmrow[y], (ull)fmn << x0);

    // load 27 channels (float4), capture raw[label], exp in place, sum
    const float* base = cm + (size_t)b * 27 * 1024 + tid * 4;
    float4 v[27];
    float4 xl = make_float4(0.f, 0.f, 0.f, 0.f);
    float4 s4 = make_float4(0.f, 0.f, 0.f, 0.f);
#pragma unroll
    for (int c = 0; c < 27; ++c) {
      float4 r = *(const float4*)(base + (size_t)c * 1024);
      xl.x = (c == labk[0]) ? r.x : xl.x;
      xl.y = (c == labk[1]) ? r.y : xl.y;
      xl.z = (c == labk[2]) ? r.z : xl.z;
      xl.w = (c == labk[3]) ? r.w : xl.w;
      r.x = __expf(r.x); r.y = __expf(r.y); r.z = __expf(r.z); r.w = __expf(r.w);
      v[c] = r;
      s4.x += r.x; s4.y += r.y; s4.z += r.z; s4.w += r.w;
    }
    float4 inv;
    inv.x = 1.f / s4.x; inv.y = 1.f / s4.y; inv.z = 1.f / s4.z; inv.w = 1.f / s4.w;
    float ce_part = (__logf(s4.x) - xl.x) + (__logf(s4.y) - xl.y)
                  + (__logf(s4.z) - xl.z) + (__logf(s4.w) - xl.w);

    float* os = out_smid + (size_t)b * 26 * 1024 + tid * 4;
#pragma unroll
    for (int t = 0; t < TT; ++t) {
      float4 m1;
      m1.x = v[t + 1].x * inv.x; m1.y = v[t + 1].y * inv.y;
      m1.z = v[t + 1].z * inv.z; m1.w = v[t + 1].w * inv.w;
      *(float4*)(os + (size_t)t * 1024) = m1;
      float inp = (((cbk[0] >> t) & 1) ? m1.x : 0.f) + (((cbk[1] >> t) & 1) ? m1.y : 0.f)
                + (((cbk[2] >> t) & 1) ? m1.z : 0.f) + (((cbk[3] >> t) & 1) ? m1.w : 0.f);
      float m1p = m1.x + m1.y + m1.z + m1.w;
      float ri = wave_sum(inp);
      float rm = wave_sum(m1p);
      if (lane == 0) { s_in[wv][t] = ri; s_m1[wv][t] = rm; }
    }
    float rce = wave_sum(ce_part);
    if (lane == 0) s_ce[wv] = rce;
    __syncthreads();
    if (tid < TT) {
      float m2s = 0.f;
#pragma unroll
      for (int yy = 0; yy < 16; ++yy) m2s += (float)__popcll(s_fmrow[yy] & s_bits[tid]);
      m2s_mid[b * TT + tid] = m2s;
      inter_mid[b * TT + tid] = s_in[0][tid] + s_in[1][tid] + s_in[2][tid] + s_in[3][tid];
      m1s_mid[b * TT + tid]   = s_m1[0][tid] + s_m1[1][tid] + s_m1[2][tid] + s_m1[3][tid];
    }
    if (tid == 0) atomicAdd(&parts[128 + (b & 63)], s_ce[0] + s_ce[1] + s_ce[2] + s_ce[3]);
  } else {
    // ================= low branch: 4 b per block, one wave per b, 4 px per lane =================
    int bb = (blk - NB) * 4 + wv;
    __shared__ unsigned l_bits[4][TT];
    __shared__ unsigned l_fmrow[4][8];
    if (tid < 4 * TT) l_bits[tid / TT][tid % TT] = alow[((blk - NB) * 4 + tid / TT) * TT + tid % TT];
    __syncthreads();
    if (lane < 8) l_fmrow[wv][lane] = 0u;
    unsigned colb = 0;
    if (lane < 32) {
#pragma unroll
      for (int t = 0; t < TT; ++t) colb |= ((l_bits[wv][t] >> lane) & 1u) << t;
    }
    int y = lane >> 3;            // 0..7
    int x0 = (lane & 7) * 4;      // 0..28
    int word = x0 >> 4;
    ull r0 = fmsk[((size_t)bb * HH + 4 * y + 1) * 2 + word];
    ull r1 = fmsk[((size_t)bb * HH + 4 * y + 2) * 2 + word];
    unsigned cbk[4]; int labk[4]; int fmn = 0; float fmv[4];
#pragma unroll
    for (int k = 0; k < 4; ++k) {
      int p = (4 * (x0 + k) + 1) & 63;
      int c = (int)((r0 >> p) & 1) + (int)((r0 >> (p + 1)) & 1)
            + (int)((r1 >> p) & 1) + (int)((r1 >> (p + 1)) & 1);
      bool fm = c >= 2;
      fmv[k] = fm ? 0.f : 1.f;    // channel-0 mask value
      cbk[k] = __shfl(colb, x0 + k, 64);
      labk[k] = (fm && cbk[k]) ? __ffs((int)cbk[k]) : 0;
      if (!fm) cbk[k] = 0;
      if (fm) fmn |= 1 << k;
    }
    if (fmn) atomicOr(&l_fmrow[wv][y], (unsigned)fmn << x0);

    const float* base = cl + (size_t)bb * 27 * 256 + lane * 4;
    float4 v[27];
    float4 xl = make_float4(0.f, 0.f, 0.f, 0.f);
    float4 s4 = make_float4(0.f, 0.f, 0.f, 0.f);
#pragma unroll
    for (int c = 0; c < 27; ++c) {
      float4 r = *(const float4*)(base + (size_t)c * 256);
      xl.x = (c == labk[0]) ? r.x : xl.x;
      xl.y = (c == labk[1]) ? r.y : xl.y;
      xl.z = (c == labk[2]) ? r.z : xl.z;
      xl.w = (c == labk[3]) ? r.w : xl.w;
      r.x = __expf(r.x); r.y = __expf(r.y); r.z = __expf(r.z); r.w = __expf(r.w);
      v[c] = r;
      s4.x += r.x; s4.y += r.y; s4.z += r.z; s4.w += r.w;
    }
    float4 inv;
    inv.x = 1.f / s4.x; inv.y = 1.f / s4.y; inv.z = 1.f / s4.z; inv.w = 1.f / s4.w;
    float ce_part = (__logf(s4.x) - xl.x) + (__logf(s4.y) - xl.y)
                  + (__logf(s4.z) - xl.z) + (__logf(s4.w) - xl.w);

    float* om  = out_mask + (size_t)bb * 27 * 256 + lane * 4;
    float* osf = out_slow + (size_t)bb * 26 * 256 + lane * 4;
    *(float4*)om = make_float4(fmv[0], fmv[1], fmv[2], fmv[3]);
    float keep_in = 0.f, keep_m1 = 0.f;
#pragma unroll
    for (int t = 0; t < TT; ++t) {
      float4 m1;
      m1.x = v[t + 1].x * inv.x; m1.y = v[t + 1].y * inv.y;
      m1.z = v[t + 1].z * inv.z; m1.w = v[t + 1].w * inv.w;
      *(float4*)(osf + (size_t)t * 256) = m1;
      float4 m2f;
      m2f.x = ((cbk[0] >> t) & 1) ? 1.f : 0.f;
      m2f.y = ((cbk[1] >> t) & 1) ? 1.f : 0.f;
      m2f.z = ((cbk[2] >> t) & 1) ? 1.f : 0.f;
      m2f.w = ((cbk[3] >> t) & 1) ? 1.f : 0.f;
      *(float4*)(om + (size_t)(t + 1) * 256) = m2f;
      float inp = m2f.x * m1.x + m2f.y * m1.y + m2f.z * m1.z + m2f.w * m1.w;
      float m1p = m1.x + m1.y + m1.z + m1.w;
      float ri = wave_sum(inp);
      float rm = wave_sum(m1p);
      keep_in = (lane == t) ? ri : keep_in;
      keep_m1 = (lane == t) ? rm : keep_m1;
    }
    float rce = wave_sum(ce_part);
    if (lane < TT) {
      float m2s = 0.f;
#pragma unroll
      for (int yy = 0; yy < 8; ++yy) m2s += (float)__popc(l_fmrow[wv][yy] & l_bits[wv][lane]);
      m2s_low[bb * TT + lane] = m2s;
      inter_low[bb * TT + lane] = keep_in;
      m1s_low[bb * TT + lane] = keep_m1;
    }
    if (lane == 0) atomicAdd(&parts[192 + (bb & 63)], rce);
  }
}

// ---------------- Phase 4: finalize scalars ----------------
__global__ __launch_bounds__(1024) void k_final(
    const float* __restrict__ parts, const float* __restrict__ seg_b,
    const float* __restrict__ inter_mid, const float* __restrict__ m1s_mid,
    const float* __restrict__ m2s_mid,
    const float* __restrict__ inter_low, const float* __restrict__ m1s_low,
    const float* __restrict__ m2s_low,
    const int* __restrict__ length, const int* __restrict__ iter_p,
    float* __restrict__ out)
{
  int tid = threadIdx.x;
  float dm = 0.f, dl = 0.f;
  for (int i = tid; i < NB * TT; i += 1024) {
    int b = i / TT, t = i - b * TT;
    int n = length[b] - 1;
    if (t < n) {
      float inv_n = 1.f / (float)n;
      dm += (1.f - (2.f * inter_mid[i] + 1.f) / (m1s_mid[i] + m2s_mid[i] + 1.f)) * inv_n;
      dl += (1.f - (2.f * inter_low[i] + 1.f) / (m1s_low[i] + m2s_low[i] + 1.f)) * inv_n;
    }
  }
  float ss = 0.f, sel = 0.f, ssel = 0.f;
  for (int b = tid; b < NB; b += 1024) {
    float v = seg_b[b];
    ss += v;
    float val = v * (1.f / 4096.f);
    if (val < 1.f) { sel += 1.f; ssel += val; }
  }
  float pv = (tid < 256) ? parts[tid] : 0.f;   // wave 0:irr 1:cor 2:celm 3:cell
  dm = wave_sum(dm); dl = wave_sum(dl); ss = wave_sum(ss);
  sel = wave_sum(sel); ssel = wave_sum(ssel); pv = wave_sum(pv);
  __shared__ float red[6][16];
  int wv = tid >> 6;
  if ((tid & 63) == 0) {
    red[0][wv] = dm; red[1][wv] = dl; red[2][wv] = ss;
    red[3][wv] = sel; red[4][wv] = ssel; red[5][wv] = pv;
  }
  __syncthreads();
  if (tid == 0) {
    float DM = 0, DL = 0, SS = 0, SEL = 0, SSEL = 0;
    for (int i = 0; i < 16; ++i) {
      DM += red[0][i]; DL += red[1][i]; SS += red[2][i];
      SEL += red[3][i]; SSEL += red[4][i];
    }
    float IRR = red[5][0], COR = red[5][1], CELM = red[5][2], CELL = red[5][3];
    float pred = (iter_p[0] > 20000) ? (SSEL / fmaxf(SEL, 1.f)) : (SS / 2097152.f);
    out[0] = pred;
    out[1] = COR / 2097152.f + IRR;
    out[2] = CELL / 131072.f + DL / 512.f;   // loss_low
    out[3] = CELM / 524288.f + DM / 512.f;   // loss_middle
  }
}

extern "C" void kernel_launch(void* const* d_in, const int* in_sizes, int n_in,
                              void* d_out, int out_size, void* d_ws, size_t ws_size,
                              hipStream_t stream) {
  (void)in_sizes; (void)n_in; (void)out_size; (void)ws_size;
  const float* masks  = (const float*)d_in[0];
  const float* bf     = (const float*)d_in[1];
  const float* seq    = (const float*)d_in[2];
  const float* cmid   = (const float*)d_in[3];
  const float* clow   = (const float*)d_in[4];
  const int*   length = (const int*)d_in[5];
  const int*   iter   = (const int*)d_in[6];
  const float* alpha  = (const float*)d_in[7];
  float* out = (float*)d_out;

  char* ws = (char*)d_ws;
  // zeroed region [0, 3072): parts + seg_b only (dice arrays are direct-stored now)
  float* parts     = (float*)(ws + 0);        // 256 f32 scalar-part slots
  float* seg_b     = (float*)(ws + 1024);     // 512 f32
  float* inter_mid = (float*)(ws + 3072);     // 13312 f32 each, direct-stored
  float* m1s_mid   = (float*)(ws + 56320);
  float* m2s_mid   = (float*)(ws + 109568);
  // non-accumulated scratch (fully rewritten every launch)
  ull*          amid = (ull*)(ws + 162816);          // 512*26 u64
  unsigned int* alow = (unsigned int*)(ws + 269312); // 512*26 u32
  ull*          fmsk = (ull*)(ws + 322560);          // 512*32*2 u64
  float*        wsA  = (float*)(ws + 584704);        // 512*128 f32 (dead after k_phase2)
  // low dice arrays alias wsA region (direct-stored by k_chars after phase2's last wsA read)
  float* inter_low = (float*)(ws + 584704);
  float* m1s_low   = (float*)(ws + 637952);
  float* m2s_low   = (float*)(ws + 691200);          // ends 744448

  hipMemsetAsync(d_ws, 0, 3072, stream);

  k_phase1<<<NB, 128, 0, stream>>>(seq, length, alpha, wsA, amid, alow, parts);
  k_phase2<<<(NB * HH * WW) / 256, 256, 0, stream>>>(masks, bf, wsA, seg_b, parts, fmsk);

  float* out_mask = out + 4;
  float* out_smid = out + 4 + 3538944;
  float* out_slow = out + 4 + 3538944 + 13631488;

  k_chars<<<NB + NB / 4, 256, 0, stream>>>(cmid, clow, fmsk, amid, alow,
                                           out_mask, out_smid, out_slow, parts,
                                           inter_mid, m1s_mid, m2s_mid,
                                           inter_low, m1s_low, m2s_low);
  k_final<<<1, 1024, 0, stream>>>(parts, seg_b, inter_mid, m1s_mid, m2s_mid,
                                  inter_low, m1s_low, m2s_low, length, iter, out);
}

// Round 4
// 69.211 us; speedup vs baseline: 3.7371x; 1.6938x over previous
//
#include <hip/hip_runtime.h>
#include <hip/hip_bf16.h>
#include <math.h>

#define NB 512
#define TT 26
#define LL 64
#define HH 32
#define WW 128

typedef unsigned long long ull;

__device__ __forceinline__ float wave_sum(float v) {
#pragma unroll
  for (int o = 32; o > 0; o >>= 1) v += __shfl_xor(v, o, 64);
  return v;
}

template<int CTRL, int RM>
__device__ __forceinline__ float dpp_add(float x) {
  int y = __builtin_amdgcn_update_dpp(0, __float_as_int(x), CTRL, RM, 0xf, true);
  return x + __int_as_float(y);
}
// sum across 64 lanes via DPP (VALU pipe only); result valid in lane 63
__device__ __forceinline__ float wave_red63(float x) {
  x = dpp_add<0x111, 0xf>(x);   // row_shr:1
  x = dpp_add<0x112, 0xf>(x);   // row_shr:2
  x = dpp_add<0x114, 0xf>(x);   // row_shr:4
  x = dpp_add<0x118, 0xf>(x);   // row_shr:8  -> lane15 of each row has row sum
  x = dpp_add<0x142, 0xa>(x);   // row_bcast15 -> rows 1,3
  x = dpp_add<0x143, 0xc>(x);   // row_bcast31 -> rows 2,3; lane63 = total
  return x;
}

// ---------------- Phase 1: per-sample attention work ----------------
__global__ __launch_bounds__(128) void k_phase1(
    const float* __restrict__ seq, const int* __restrict__ length,
    const float* __restrict__ alpha_p, float* __restrict__ wsA,
    ull* __restrict__ amid, unsigned int* __restrict__ alow,
    float* __restrict__ irr_part)
{
  int b = blockIdx.x;
  int tid = threadIdx.x;
  __shared__ float att[LL * TT];
  __shared__ float wpart[2];
  const float* sb = seq + (size_t)b * (LL * TT);
  for (int i = tid; i < LL * TT; i += 128) att[i] = sb[i];
  __syncthreads();
  int n = length[b] - 1;
  float alpha = alpha_p[0];

  // interp column w: linear resize 64 -> 128, half-pixel, clamped
  int w = tid;
  int k = w >> 1;
  int i0, i1; float c0, c1;
  if ((w & 1) == 0) {
    if (k == 0) { i0 = 0; i1 = 0; c0 = 1.f; c1 = 0.f; }
    else        { i0 = k - 1; i1 = k; c0 = 0.25f; c1 = 0.75f; }
  } else {
    if (k == 63) { i0 = 63; i1 = 63; c0 = 1.f; c1 = 0.f; }
    else         { i0 = k; i1 = k + 1; c0 = 0.75f; c1 = 0.25f; }
  }
  float S = 0.f, S2 = 0.f, A = 0.f;
  for (int t = 0; t < n; ++t) {
    float v = c0 * att[i0 * TT + t] + c1 * att[i1 * TT + t];
    float s = v * v;
    S += s; S2 += s * s;
    A += 1.f / (1.f + __expf(-70.f * (v - 0.1f)));
  }
  wsA[b * WW + w] = A;

  float c = S * S - S2;
  c = wave_sum(c);
  if ((tid & 63) == 0) wpart[tid >> 6] = c;
  __syncthreads();
  if (tid == 0) irr_part[b] = 0.5f * (wpart[0] + wpart[1]) / (float)n;

  if (tid < 64) {
    int x = tid;                       // middle: identity resize, 64 cols
    for (int t = 0; t < TT; ++t) {
      bool pred = (t < n) && (att[x * TT + t] > alpha);
      ull m = __ballot(pred);
      if (x == 0) amid[b * TT + t] = m;
    }
  } else {
    int x = tid - 64;                  // low: pairwise mean, 32 cols
    for (int t = 0; t < TT; ++t) {
      bool pred = (x < 32) && (t < n) &&
                  (0.5f * (att[(2 * x) * TT + t] + att[(2 * x + 1) * TT + t]) > alpha);
      ull m = __ballot(pred);
      if (x == 0) alow[b * TT + t] = (unsigned int)m;
    }
  }
}

// ---------------- Phase 2: seg CE + correct CE + fore bitmask ----------------
// 2048 blocks of 256; block (b, quarter) covers px [q*1024, q*1024+1024)
__global__ __launch_bounds__(256) void k_phase2(
    const float* __restrict__ masks, const float* __restrict__ bf,
    const float* __restrict__ wsA, float* __restrict__ seg_part,
    float* __restrict__ cor_part, ull* __restrict__ fmsk)
{
  int bid = blockIdx.x;
  int b = bid >> 2, q = bid & 3;
  int tid = threadIdx.x;
  int lane = tid & 63, wv = tid >> 6;
  const float* mb = masks + (size_t)b * 4096 + q * 1024;
  const float* fb = bf + (size_t)b * 8192 + q * 1024;

  float A = wsA[b * WW + (tid & 127)];
  float cs = fminf(fmaxf(A, 0.f), 1.f);
  float ce_fore = log1pf(__expf(1.f - 2.f * cs));

  float seg_acc = 0.f, cor_acc = 0.f;
  for (int k = 0; k < 4; ++k) {
    int px = k * 256 + tid;
    float m = mb[px];
    float b0 = fb[px];
    float b1 = fb[4096 + px];
    float mx = fmaxf(b0, b1);
    float e0 = __expf(b0 - mx), e1 = __expf(b1 - mx);
    float inv = 1.f / (e0 + e1);
    float p0 = e0 * inv, p1 = e1 * inv;
    float pm = fmaxf(p0, p1);
    float lse = pm + log1pf(__expf(-fabsf(p1 - p0)));
    seg_acc += lse - ((m > 0.5f) ? p1 : p0);
    bool fore = b1 > b0;
    cor_acc += fore ? ce_fore : 0.313261687518222834f;
    ull fbm = __ballot(fore);
    if (lane == 0) fmsk[(size_t)b * 64 + q * 16 + k * 4 + wv] = fbm;
  }
  seg_acc = wave_sum(seg_acc);
  cor_acc = wave_sum(cor_acc);
  __shared__ float ps[4], pc[4];
  if (lane == 0) { ps[wv] = seg_acc; pc[wv] = cor_acc; }
  __syncthreads();
  if (tid == 0) {
    seg_part[bid] = ps[0] + ps[1] + ps[2] + ps[3];
    cor_part[bid] = pc[0] + pc[1] + pc[2] + pc[3];
  }
}

// ---------------- Phase 3 (fused): low blocks [0,128), mid blocks [128, 640) ----------------
// 512 threads per block, 2 px per thread (float2)
__global__ __launch_bounds__(512) void k_chars(
    const float* __restrict__ cm, const float* __restrict__ cl,
    const ull* __restrict__ fmsk, const ull* __restrict__ amid,
    const unsigned int* __restrict__ alow,
    float* __restrict__ out_mask, float* __restrict__ out_smid,
    float* __restrict__ out_slow,
    float* __restrict__ celm_part, float* __restrict__ cell_part,
    float* __restrict__ inter_mid, float* __restrict__ m1s_mid, float* __restrict__ m2s_mid,
    float* __restrict__ inter_low, float* __restrict__ m1s_low, float* __restrict__ m2s_low)
{
  int blk = blockIdx.x;
  int tid = threadIdx.x;
  int lane = tid & 63, wv = tid >> 6;

  __shared__ float s_red_in[8][TT], s_red_m1[8][TT], s_ce[8];

  if (blk < 128) {
    // ============ low branch: 4 b per block, wave-pair per b, 2 px/lane ============
    int bI = wv >> 1;                       // 0..3 within block
    int bb = blk * 4 + bI;
    __shared__ unsigned l_bits[4][TT];
    __shared__ unsigned l_fmrow[4][8];
    if (tid < 4 * TT) l_bits[tid / TT][tid % TT] = alow[(blk * 4 + tid / TT) * TT + tid % TT];
    if (tid < 32) l_fmrow[tid >> 3][tid & 7] = 0u;
    __syncthreads();

    int Lp = lane + 64 * (wv & 1);          // 0..127 within b
    int px0 = 2 * Lp;                       // even px in [0,256)
    int y = px0 >> 5;                       // 0..7
    int x0 = px0 & 31;                      // even
    unsigned colb = 0;
    {
      int xcol = lane & 31;
#pragma unroll
      for (int t = 0; t < TT; ++t) colb |= ((l_bits[bI][t] >> xcol) & 1u) << t;
    }
    int word = x0 >> 4;
    ull r0 = fmsk[(size_t)bb * 64 + (4 * y + 1) * 2 + word];
    ull r1 = fmsk[(size_t)bb * 64 + (4 * y + 2) * 2 + word];
    unsigned cbk[2]; int labk[2]; int fmn = 0; float fmv[2];
#pragma unroll
    for (int k = 0; k < 2; ++k) {
      int p = (4 * (x0 + k) + 1) & 63;
      int c = (int)((r0 >> p) & 1) + (int)((r0 >> (p + 1)) & 1)
            + (int)((r1 >> p) & 1) + (int)((r1 >> (p + 1)) & 1);
      bool fm = c >= 2;
      fmv[k] = fm ? 0.f : 1.f;
      cbk[k] = __shfl(colb, x0 + k, 64);
      labk[k] = (fm && cbk[k]) ? __ffs((int)cbk[k]) : 0;
      if (!fm) cbk[k] = 0;
      if (fm) fmn |= 1 << k;
    }
    if (fmn) atomicOr(&l_fmrow[bI][y], (unsigned)fmn << x0);

    const float* base = cl + (size_t)bb * 27 * 256 + px0;
    float2 v[27];
    float xl0 = 0.f, xl1 = 0.f, s0 = 0.f, s1 = 0.f;
#pragma unroll
    for (int c = 0; c < 27; ++c) {
      float2 r = *(const float2*)(base + (size_t)c * 256);
      xl0 = (c == labk[0]) ? r.x : xl0;
      xl1 = (c == labk[1]) ? r.y : xl1;
      r.x = __expf(r.x); r.y = __expf(r.y);
      v[c] = r;
      s0 += r.x; s1 += r.y;
    }
    float inv0 = 1.f / s0, inv1 = 1.f / s1;
    float ce_part = (__logf(s0) - xl0) + (__logf(s1) - xl1);

    float* om  = out_mask + (size_t)bb * 27 * 256 + px0;
    float* osf = out_slow + (size_t)bb * 26 * 256 + px0;
    *(float2*)om = make_float2(fmv[0], fmv[1]);
#pragma unroll
    for (int t = 0; t < TT; ++t) {
      float2 m1 = make_float2(v[t + 1].x * inv0, v[t + 1].y * inv1);
      *(float2*)(osf + (size_t)t * 256) = m1;
      float b0f = ((cbk[0] >> t) & 1) ? 1.f : 0.f;
      float b1f = ((cbk[1] >> t) & 1) ? 1.f : 0.f;
      *(float2*)(om + (size_t)(t + 1) * 256) = make_float2(b0f, b1f);
      float ri = wave_red63(b0f * m1.x + b1f * m1.y);
      float rm = wave_red63(m1.x + m1.y);
      if (lane == 63) { s_red_in[wv][t] = ri; s_red_m1[wv][t] = rm; }
    }
    float rce = wave_red63(ce_part);
    if (lane == 63) s_ce[wv] = rce;
    __syncthreads();
    if (!(wv & 1)) {
      if (lane < TT) {
        float m2v = 0.f;
#pragma unroll
        for (int yy = 0; yy < 8; ++yy) m2v += (float)__popc(l_fmrow[bI][yy] & l_bits[bI][lane]);
        m2s_low[bb * TT + lane] = m2v;
        inter_low[bb * TT + lane] = s_red_in[wv][lane] + s_red_in[wv + 1][lane];
        m1s_low[bb * TT + lane]   = s_red_m1[wv][lane] + s_red_m1[wv + 1][lane];
      }
      if (lane == 32) cell_part[bb] = s_ce[wv] + s_ce[wv + 1];
    }
  } else {
    // ============ mid branch: one block per b, 2 px/thread ============
    int b = blk - 128;
    __shared__ ull s_bits[TT];
    __shared__ unsigned s_cols[64];
    __shared__ ull s_fmrow[16];
    if (tid < TT) s_bits[tid] = amid[b * TT + tid];
    __syncthreads();
    if (tid < 64) {
      unsigned cb = 0;
#pragma unroll
      for (int t = 0; t < TT; ++t) cb |= (unsigned)((s_bits[t] >> tid) & 1ULL) << t;
      s_cols[tid] = cb;
    } else if (tid < 80) {
      s_fmrow[tid - 64] = 0ULL;
    }
    __syncthreads();

    int px0 = 2 * tid;                 // even px in [0,1024)
    int y = px0 >> 6;                  // 0..15
    int x0 = px0 & 63;                 // even
    int word = x0 >> 5;
    ull r0 = fmsk[(size_t)b * 64 + 4 * y + word];
    ull r1 = fmsk[(size_t)b * 64 + 4 * y + 2 + word];
    unsigned cbk[2]; int labk[2]; int fmn = 0;
#pragma unroll
    for (int k = 0; k < 2; ++k) {
      int p = (2 * (x0 + k)) & 63;
      int c = (int)((r0 >> p) & 1) + (int)((r0 >> (p + 1)) & 1)
            + (int)((r1 >> p) & 1) + (int)((r1 >> (p + 1)) & 1);
      bool fm = c >= 2;
      cbk[k] = s_cols[x0 + k];
      labk[k] = (fm && cbk[k]) ? __ffs((int)cbk[k]) : 0;
      if (!fm) cbk[k] = 0;
      if (fm) fmn |= 1 << k;
    }
    if (fmn) atomicOr(&s_fmrow[y], (ull)fmn << x0);

    const float* base = cm + (size_t)b * 27 * 1024 + px0;
    float2 v[27];
    float xl0 = 0.f, xl1 = 0.f, s0 = 0.f, s1 = 0.f;
#pragma unroll
    for (int c = 0; c < 27; ++c) {
      float2 r = *(const float2*)(base + (size_t)c * 1024);
      xl0 = (c == labk[0]) ? r.x : xl0;
      xl1 = (c == labk[1]) ? r.y : xl1;
      r.x = __expf(r.x); r.y = __expf(r.y);
      v[c] = r;
      s0 += r.x; s1 += r.y;
    }
    float inv0 = 1.f / s0, inv1 = 1.f / s1;
    float ce_part = (__logf(s0) - xl0) + (__logf(s1) - xl1);

    float* os = out_smid + (size_t)b * 26 * 1024 + px0;
#pragma unroll
    for (int t = 0; t < TT; ++t) {
      float2 m1 = make_float2(v[t + 1].x * inv0, v[t + 1].y * inv1);
      *(float2*)(os + (size_t)t * 1024) = m1;
      float inp = (((cbk[0] >> t) & 1) ? m1.x : 0.f) + (((cbk[1] >> t) & 1) ? m1.y : 0.f);
      float ri = wave_red63(inp);
      float rm = wave_red63(m1.x + m1.y);
      if (lane == 63) { s_red_in[wv][t] = ri; s_red_m1[wv][t] = rm; }
    }
    float rce = wave_red63(ce_part);
    if (lane == 63) s_ce[wv] = rce;
    __syncthreads();
    if (tid < TT) {
      float m2v = 0.f;
#pragma unroll
      for (int yy = 0; yy < 16; ++yy) m2v += (float)__popcll(s_fmrow[yy] & s_bits[tid]);
      m2s_mid[b * TT + tid] = m2v;
      float si = 0.f, sm = 0.f;
#pragma unroll
      for (int w = 0; w < 8; ++w) { si += s_red_in[w][tid]; sm += s_red_m1[w][tid]; }
      inter_mid[b * TT + tid] = si;
      m1s_mid[b * TT + tid] = sm;
    }
    if (tid == 26) {
      float c8 = 0.f;
#pragma unroll
      for (int w = 0; w < 8; ++w) c8 += s_ce[w];
      celm_part[b] = c8;
    }
  }
}

// ---------------- Phase 4: finalize scalars ----------------
__global__ __launch_bounds__(1024) void k_final(
    const float* __restrict__ seg_part, const float* __restrict__ cor_part,
    const float* __restrict__ irr_part, const float* __restrict__ celm_part,
    const float* __restrict__ cell_part,
    const float* __restrict__ inter_mid, const float* __restrict__ m1s_mid,
    const float* __restrict__ m2s_mid,
    const float* __restrict__ inter_low, const float* __restrict__ m1s_low,
    const float* __restrict__ m2s_low,
    const int* __restrict__ length, const int* __restrict__ iter_p,
    float* __restrict__ out)
{
  int tid = threadIdx.x;
  float dm = 0.f, dl = 0.f;
  for (int i = tid; i < NB * TT; i += 1024) {
    int b = i / TT, t = i - b * TT;
    int n = length[b] - 1;
    if (t < n) {
      float inv_n = 1.f / (float)n;
      dm += (1.f - (2.f * inter_mid[i] + 1.f) / (m1s_mid[i] + m2s_mid[i] + 1.f)) * inv_n;
      dl += (1.f - (2.f * inter_low[i] + 1.f) / (m1s_low[i] + m2s_low[i] + 1.f)) * inv_n;
    }
  }
  float ss = 0.f, sel = 0.f, ssel = 0.f;
  float irr = 0.f, celm = 0.f, cell = 0.f;
  for (int b = tid; b < NB; b += 1024) {
    float v = seg_part[4 * b] + seg_part[4 * b + 1] + seg_part[4 * b + 2] + seg_part[4 * b + 3];
    ss += v;
    float val = v * (1.f / 4096.f);
    if (val < 1.f) { sel += 1.f; ssel += val; }
    irr += irr_part[b]; celm += celm_part[b]; cell += cell_part[b];
  }
  float cor = 0.f;
  for (int i = tid; i < 4 * NB; i += 1024) cor += cor_part[i];

  dm = wave_sum(dm); dl = wave_sum(dl); ss = wave_sum(ss);
  sel = wave_sum(sel); ssel = wave_sum(ssel);
  irr = wave_sum(irr); celm = wave_sum(celm); cell = wave_sum(cell);
  cor = wave_sum(cor);
  __shared__ float red[9][16];
  int wv = tid >> 6;
  if ((tid & 63) == 0) {
    red[0][wv] = dm; red[1][wv] = dl; red[2][wv] = ss; red[3][wv] = sel;
    red[4][wv] = ssel; red[5][wv] = irr; red[6][wv] = celm; red[7][wv] = cell;
    red[8][wv] = cor;
  }
  __syncthreads();
  if (tid == 0) {
    float a[9];
#pragma unroll
    for (int j = 0; j < 9; ++j) {
      float s = 0.f;
      for (int i = 0; i < 16; ++i) s += red[j][i];
      a[j] = s;
    }
    float pred = (iter_p[0] > 20000) ? (a[4] / fmaxf(a[3], 1.f)) : (a[2] / 2097152.f);
    out[0] = pred;
    out[1] = a[8] / 2097152.f + a[5];
    out[2] = a[7] / 131072.f + a[1] / 512.f;   // loss_low
    out[3] = a[6] / 524288.f + a[0] / 512.f;   // loss_middle
  }
}

extern "C" void kernel_launch(void* const* d_in, const int* in_sizes, int n_in,
                              void* d_out, int out_size, void* d_ws, size_t ws_size,
                              hipStream_t stream) {
  (void)in_sizes; (void)n_in; (void)out_size; (void)ws_size;
  const float* masks  = (const float*)d_in[0];
  const float* bf     = (const float*)d_in[1];
  const float* seq    = (const float*)d_in[2];
  const float* cmid   = (const float*)d_in[3];
  const float* clow   = (const float*)d_in[4];
  const int*   length = (const int*)d_in[5];
  const int*   iter   = (const int*)d_in[6];
  const float* alpha  = (const float*)d_in[7];
  float* out = (float*)d_out;

  char* ws = (char*)d_ws;
  // all scratch is fully rewritten every launch -> no memset needed
  float* seg_part  = (float*)(ws + 0);        // 2048 f32
  float* cor_part  = (float*)(ws + 8192);     // 2048 f32
  float* irr_part  = (float*)(ws + 16384);    // 512 f32
  float* celm_part = (float*)(ws + 18432);    // 512 f32
  float* cell_part = (float*)(ws + 20480);    // 512 f32
  float* inter_mid = (float*)(ws + 22528);    // 13312 f32
  float* m1s_mid   = (float*)(ws + 75776);
  float* m2s_mid   = (float*)(ws + 129024);
  ull*          amid = (ull*)(ws + 182272);          // 512*26 u64
  unsigned int* alow = (unsigned int*)(ws + 288768); // 512*26 u32
  ull*          fmsk = (ull*)(ws + 342016);          // 512*64 u64
  float*        wsA  = (float*)(ws + 604160);        // 512*128 f32 (dead after phase2)
  // low dice arrays alias wsA region (written in k_chars, after wsA's last read)
  float* inter_low = (float*)(ws + 604160);
  float* m1s_low   = (float*)(ws + 657408);
  float* m2s_low   = (float*)(ws + 710656);          // ends 763904

  k_phase1<<<NB, 128, 0, stream>>>(seq, length, alpha, wsA, amid, alow, irr_part);
  k_phase2<<<NB * 4, 256, 0, stream>>>(masks, bf, wsA, seg_part, cor_part, fmsk);

  float* out_mask = out + 4;
  float* out_smid = out + 4 + 3538944;
  float* out_slow = out + 4 + 3538944 + 13631488;

  k_chars<<<128 + NB, 512, 0, stream>>>(cmid, clow, fmsk, amid, alow,
                                        out_mask, out_smid, out_slow,
                                        celm_part, cell_part,
                                        inter_mid, m1s_mid, m2s_mid,
                                        inter_low, m1s_low, m2s_low);
  k_final<<<1, 1024, 0, stream>>>(seg_part, cor_part, irr_part, celm_part, cell_part,
                                  inter_mid, m1s_mid, m2s_mid,
                                  inter_low, m1s_low, m2s_low, length, iter, out);
}

// Round 5
// 68.551 us; speedup vs baseline: 3.7731x; 1.0096x over previous
//
#include <hip/hip_runtime.h>
#include <hip/hip_bf16.h>
#include <math.h>

#define NB 512
#define TT 26
#define LL 64
#define HH 32
#define WW 128

typedef unsigned long long ull;

__device__ __forceinline__ float wave_sum(float v) {
#pragma unroll
  for (int o = 32; o > 0; o >>= 1) v += __shfl_xor(v, o, 64);
  return v;
}

template<int CTRL, int RM>
__device__ __forceinline__ float dpp_add(float x) {
  int y = __builtin_amdgcn_update_dpp(0, __float_as_int(x), CTRL, RM, 0xf, true);
  return x + __int_as_float(y);
}
// sum across 64 lanes via DPP (VALU pipe only); result valid in lane 63
__device__ __forceinline__ float wave_red63(float x) {
  x = dpp_add<0x111, 0xf>(x);   // row_shr:1
  x = dpp_add<0x112, 0xf>(x);   // row_shr:2
  x = dpp_add<0x114, 0xf>(x);   // row_shr:4
  x = dpp_add<0x118, 0xf>(x);   // row_shr:8
  x = dpp_add<0x142, 0xa>(x);   // row_bcast15 -> rows 1,3
  x = dpp_add<0x143, 0xc>(x);   // row_bcast31 -> rows 2,3; lane63 = total
  return x;
}

// ---------------- Phase 1: per-sample attention work ----------------
__global__ __launch_bounds__(128) void k_phase1(
    const float* __restrict__ seq, const int* __restrict__ length,
    const float* __restrict__ alpha_p, float* __restrict__ wsA,
    ull* __restrict__ amid, unsigned int* __restrict__ alow,
    float* __restrict__ irr_part)
{
  int b = blockIdx.x;
  int tid = threadIdx.x;
  __shared__ float att[LL * TT];
  __shared__ float wpart[2];
  const float* sb = seq + (size_t)b * (LL * TT);
  for (int i = tid; i < LL * TT; i += 128) att[i] = sb[i];
  __syncthreads();
  int n = length[b] - 1;
  float alpha = alpha_p[0];

  int w = tid;
  int k = w >> 1;
  int i0, i1; float c0, c1;
  if ((w & 1) == 0) {
    if (k == 0) { i0 = 0; i1 = 0; c0 = 1.f; c1 = 0.f; }
    else        { i0 = k - 1; i1 = k; c0 = 0.25f; c1 = 0.75f; }
  } else {
    if (k == 63) { i0 = 63; i1 = 63; c0 = 1.f; c1 = 0.f; }
    else         { i0 = k; i1 = k + 1; c0 = 0.75f; c1 = 0.25f; }
  }
  float S = 0.f, S2 = 0.f, A = 0.f;
  for (int t = 0; t < n; ++t) {
    float v = c0 * att[i0 * TT + t] + c1 * att[i1 * TT + t];
    float s = v * v;
    S += s; S2 += s * s;
    A += 1.f / (1.f + __expf(-70.f * (v - 0.1f)));
  }
  wsA[b * WW + w] = A;

  float c = S * S - S2;
  c = wave_sum(c);
  if ((tid & 63) == 0) wpart[tid >> 6] = c;
  __syncthreads();
  if (tid == 0) irr_part[b] = 0.5f * (wpart[0] + wpart[1]) / (float)n;

  if (tid < 64) {
    int x = tid;                       // middle: identity resize, 64 cols
    for (int t = 0; t < TT; ++t) {
      bool pred = (t < n) && (att[x * TT + t] > alpha);
      ull m = __ballot(pred);
      if (x == 0) amid[b * TT + t] = m;
    }
  } else {
    int x = tid - 64;                  // low: pairwise mean, 32 cols
    for (int t = 0; t < TT; ++t) {
      bool pred = (x < 32) && (t < n) &&
                  (0.5f * (att[(2 * x) * TT + t] + att[(2 * x + 1) * TT + t]) > alpha);
      ull m = __ballot(pred);
      if (x == 0) alow[b * TT + t] = (unsigned int)m;
    }
  }
}

// ---------------- Phase 2: seg CE + correct CE + fore bitmask ----------------
__global__ __launch_bounds__(256) void k_phase2(
    const float* __restrict__ masks, const float* __restrict__ bf,
    const float* __restrict__ wsA, float* __restrict__ seg_part,
    float* __restrict__ cor_part, ull* __restrict__ fmsk)
{
  int bid = blockIdx.x;
  int b = bid >> 2, q = bid & 3;
  int tid = threadIdx.x;
  int lane = tid & 63, wv = tid >> 6;
  const float* mb = masks + (size_t)b * 4096 + q * 1024;
  const float* fb = bf + (size_t)b * 8192 + q * 1024;

  float A = wsA[b * WW + (tid & 127)];
  float cs = fminf(fmaxf(A, 0.f), 1.f);
  float ce_fore = log1pf(__expf(1.f - 2.f * cs));

  float seg_acc = 0.f, cor_acc = 0.f;
  for (int k = 0; k < 4; ++k) {
    int px = k * 256 + tid;
    float m = mb[px];
    float b0 = fb[px];
    float b1 = fb[4096 + px];
    float mx = fmaxf(b0, b1);
    float e0 = __expf(b0 - mx), e1 = __expf(b1 - mx);
    float inv = 1.f / (e0 + e1);
    float p0 = e0 * inv, p1 = e1 * inv;
    float pm = fmaxf(p0, p1);
    float lse = pm + log1pf(__expf(-fabsf(p1 - p0)));
    seg_acc += lse - ((m > 0.5f) ? p1 : p0);
    bool fore = b1 > b0;
    cor_acc += fore ? ce_fore : 0.313261687518222834f;
    ull fbm = __ballot(fore);
    if (lane == 0) fmsk[(size_t)b * 64 + q * 16 + k * 4 + wv] = fbm;
  }
  seg_acc = wave_sum(seg_acc);
  cor_acc = wave_sum(cor_acc);
  __shared__ float ps[4], pc[4];
  if (lane == 0) { ps[wv] = seg_acc; pc[wv] = cor_acc; }
  __syncthreads();
  if (tid == 0) {
    seg_part[bid] = ps[0] + ps[1] + ps[2] + ps[3];
    cor_part[bid] = pc[0] + pc[1] + pc[2] + pc[3];
  }
}

// ---------------- Phase 3 (fused, 1 px/thread): low blocks [0,256), mid blocks [256,1280) ----------------
__global__ __launch_bounds__(512) void k_chars(
    const float* __restrict__ cm, const float* __restrict__ cl,
    const ull* __restrict__ fmsk, const ull* __restrict__ amid,
    const unsigned int* __restrict__ alow,
    float* __restrict__ out_mask, float* __restrict__ out_smid,
    float* __restrict__ out_slow,
    float* __restrict__ celm_part, float* __restrict__ cell_part,
    float* __restrict__ inter_midP, float* __restrict__ m1s_midP, float* __restrict__ m2s_midP,
    float* __restrict__ inter_low, float* __restrict__ m1s_low, float* __restrict__ m2s_low)
{
  int blk = blockIdx.x;
  int tid = threadIdx.x;
  int lane = tid & 63, wv = tid >> 6;

  __shared__ float s_red_in[8][TT], s_red_m1[8][TT], s_ce[8];

  if (blk >= 256) {
    // ============ mid branch: 2 blocks per b (half h = 8 rows), 1 px/thread ============
    int bm_ = blk - 256;
    int b = bm_ >> 1, h = bm_ & 1;
    int ly = tid >> 6;               // local row 0..7 (== wv)
    int x = tid & 63;
    int px = h * 512 + tid;
    __shared__ ull s_bits[TT];
    __shared__ unsigned s_cols[64];
    __shared__ ull s_fmw[32];
    __shared__ ull s_fmrow[8];
    if (tid < TT) s_bits[tid] = amid[b * TT + tid];
    if (tid >= 32 && tid < 64) s_fmw[tid - 32] = fmsk[(size_t)b * 64 + h * 32 + (tid - 32)];
    __syncthreads();
    if (tid < 64) {
      unsigned cb = 0;
#pragma unroll
      for (int t = 0; t < TT; ++t) cb |= (unsigned)((s_bits[t] >> tid) & 1ULL) << t;
      s_cols[tid] = cb;
    }
    __syncthreads();

    int word = x >> 5;
    int p = (x & 31) * 2;
    ull r0 = s_fmw[4 * ly + word];
    ull r1 = s_fmw[4 * ly + 2 + word];
    int cnt = (int)((r0 >> p) & 1) + (int)((r0 >> (p + 1)) & 1)
            + (int)((r1 >> p) & 1) + (int)((r1 >> (p + 1)) & 1);
    bool fm = cnt >= 2;
    unsigned cbk = s_cols[x];
    int lab = (fm && cbk) ? __ffs((int)cbk) : 0;
    if (!fm) cbk = 0;
    ull bm = __ballot(fm);
    if (lane == 0) s_fmrow[wv] = bm;

    const float* base = cm + (size_t)b * 27 * 1024 + px;
    float v[27];
    float xl = 0.f, s0 = 0.f;
#pragma unroll
    for (int c = 0; c < 27; ++c) {
      float r = base[(size_t)c * 1024];
      xl = (c == lab) ? r : xl;
      r = __expf(r);
      v[c] = r;
      s0 += r;
    }
    float inv0 = 1.f / s0;
    float ce_part = __logf(s0) - xl;

    float* os = out_smid + (size_t)b * 26 * 1024 + px;
#pragma unroll
    for (int t = 0; t < TT; ++t) {
      float m1 = v[t + 1] * inv0;
      os[(size_t)t * 1024] = m1;
      float ri = wave_red63(((cbk >> t) & 1) ? m1 : 0.f);
      float rm = wave_red63(m1);
      if (lane == 63) { s_red_in[wv][t] = ri; s_red_m1[wv][t] = rm; }
    }
    float rce = wave_red63(ce_part);
    if (lane == 63) s_ce[wv] = rce;
    __syncthreads();
    if (tid < TT) {
      float m2v = 0.f;
#pragma unroll
      for (int r = 0; r < 8; ++r) m2v += (float)__popcll(s_fmrow[r] & s_bits[tid]);
      float si = 0.f, sm = 0.f;
#pragma unroll
      for (int w = 0; w < 8; ++w) { si += s_red_in[w][tid]; sm += s_red_m1[w][tid]; }
      int o = (2 * b + h) * TT + tid;
      m2s_midP[o] = m2v;
      inter_midP[o] = si;
      m1s_midP[o] = sm;
    }
    if (tid == TT) {
      float c8 = 0.f;
#pragma unroll
      for (int w = 0; w < 8; ++w) c8 += s_ce[w];
      celm_part[2 * b + h] = c8;
    }
  } else {
    // ============ low branch: 2 b per block, 1 px/thread ============
    int blkL = blk;
    int bI = tid >> 8;                // 0..1
    int bb = blkL * 2 + bI;
    int px = tid & 255;
    int y = px >> 5, x = px & 31;
    __shared__ unsigned l_bits[2][TT];
    __shared__ unsigned s_colsL[2][32];
    __shared__ ull s_fmwL[2][64];
    __shared__ unsigned s_fmrow32[2][8];
    if (tid < 2 * TT) {
      int bi = tid / TT, t = tid - bi * TT;
      l_bits[bi][t] = alow[(blkL * 2 + bi) * TT + t];
    }
    if (tid >= 128 && tid < 256) {
      int j = tid - 128;
      s_fmwL[j >> 6][j & 63] = fmsk[(size_t)(blkL * 2 + (j >> 6)) * 64 + (j & 63)];
    }
    __syncthreads();
    if (tid < 64) {
      int bi = tid >> 5, xc = tid & 31;
      unsigned cb = 0;
#pragma unroll
      for (int t = 0; t < TT; ++t) cb |= ((l_bits[bi][t] >> xc) & 1u) << t;
      s_colsL[bi][xc] = cb;
    }
    __syncthreads();

    int wb = 4 * x + 1;
    int word = wb >> 6;
    int p = wb & 63;
    ull r0 = s_fmwL[bI][(4 * y + 1) * 2 + word];
    ull r1 = s_fmwL[bI][(4 * y + 2) * 2 + word];
    int cnt = (int)((r0 >> p) & 1) + (int)((r0 >> (p + 1)) & 1)
            + (int)((r1 >> p) & 1) + (int)((r1 >> (p + 1)) & 1);
    bool fm = cnt >= 2;
    unsigned cbk = s_colsL[bI][x];
    int lab = (fm && cbk) ? __ffs((int)cbk) : 0;
    if (!fm) cbk = 0;
    ull bm = __ballot(fm);
    if (lane == 0) {
      int wq = wv & 3;
      s_fmrow32[bI][2 * wq] = (unsigned)bm;
      s_fmrow32[bI][2 * wq + 1] = (unsigned)(bm >> 32);
    }

    const float* base = cl + (size_t)bb * 27 * 256 + px;
    float v[27];
    float xl = 0.f, s0 = 0.f;
#pragma unroll
    for (int c = 0; c < 27; ++c) {
      float r = base[(size_t)c * 256];
      xl = (c == lab) ? r : xl;
      r = __expf(r);
      v[c] = r;
      s0 += r;
    }
    float inv0 = 1.f / s0;
    float ce_part = __logf(s0) - xl;

    float* om  = out_mask + (size_t)bb * 27 * 256 + px;
    float* osf = out_slow + (size_t)bb * 26 * 256 + px;
    om[0] = fm ? 0.f : 1.f;
#pragma unroll
    for (int t = 0; t < TT; ++t) {
      float m1 = v[t + 1] * inv0;
      osf[(size_t)t * 256] = m1;
      bool m2 = (cbk >> t) & 1;
      om[(size_t)(t + 1) * 256] = m2 ? 1.f : 0.f;
      float ri = wave_red63(m2 ? m1 : 0.f);
      float rm = wave_red63(m1);
      if (lane == 63) { s_red_in[wv][t] = ri; s_red_m1[wv][t] = rm; }
    }
    float rce = wave_red63(ce_part);
    if (lane == 63) s_ce[wv] = rce;
    __syncthreads();
    if (tid < 2 * TT) {
      int bi = tid / TT, t = tid - bi * TT;
      float m2v = 0.f;
#pragma unroll
      for (int r = 0; r < 8; ++r) m2v += (float)__popc(s_fmrow32[bi][r] & l_bits[bi][t]);
      float si = 0.f, sm = 0.f;
#pragma unroll
      for (int w = 0; w < 4; ++w) { si += s_red_in[bi * 4 + w][t]; sm += s_red_m1[bi * 4 + w][t]; }
      int o = (blkL * 2 + bi) * TT + t;
      m2s_low[o] = m2v;
      inter_low[o] = si;
      m1s_low[o] = sm;
    }
    if (tid >= 2 * TT && tid < 2 * TT + 2) {
      int bi = tid - 2 * TT;
      cell_part[blkL * 2 + bi] = s_ce[bi * 4] + s_ce[bi * 4 + 1] + s_ce[bi * 4 + 2] + s_ce[bi * 4 + 3];
    }
  }
}

// ---------------- Phase 4: finalize scalars ----------------
__global__ __launch_bounds__(1024) void k_final(
    const float* __restrict__ seg_part, const float* __restrict__ cor_part,
    const float* __restrict__ irr_part, const float* __restrict__ celm_part,
    const float* __restrict__ cell_part,
    const float* __restrict__ inter_midP, const float* __restrict__ m1s_midP,
    const float* __restrict__ m2s_midP,
    const float* __restrict__ inter_low, const float* __restrict__ m1s_low,
    const float* __restrict__ m2s_low,
    const int* __restrict__ length, const int* __restrict__ iter_p,
    float* __restrict__ out)
{
  int tid = threadIdx.x;
  float dm = 0.f, dl = 0.f;
  for (int i = tid; i < NB * TT; i += 1024) {
    int b = i / TT, t = i - b * TT;
    int n = length[b] - 1;
    if (t < n) {
      float inv_n = 1.f / (float)n;
      int o0 = (2 * b) * TT + t, o1 = (2 * b + 1) * TT + t;
      float im = inter_midP[o0] + inter_midP[o1];
      float mm = m1s_midP[o0] + m1s_midP[o1];
      float m2 = m2s_midP[o0] + m2s_midP[o1];
      dm += (1.f - (2.f * im + 1.f) / (mm + m2 + 1.f)) * inv_n;
      dl += (1.f - (2.f * inter_low[i] + 1.f) / (m1s_low[i] + m2s_low[i] + 1.f)) * inv_n;
    }
  }
  float ss = 0.f, sel = 0.f, ssel = 0.f;
  float irr = 0.f, cell = 0.f;
  for (int b = tid; b < NB; b += 1024) {
    float v = seg_part[4 * b] + seg_part[4 * b + 1] + seg_part[4 * b + 2] + seg_part[4 * b + 3];
    ss += v;
    float val = v * (1.f / 4096.f);
    if (val < 1.f) { sel += 1.f; ssel += val; }
    irr += irr_part[b]; cell += cell_part[b];
  }
  float cor = 0.f, celm = 0.f;
  for (int i = tid; i < 4 * NB; i += 1024) cor += cor_part[i];
  for (int i = tid; i < 2 * NB; i += 1024) celm += celm_part[i];

  dm = wave_sum(dm); dl = wave_sum(dl); ss = wave_sum(ss);
  sel = wave_sum(sel); ssel = wave_sum(ssel);
  irr = wave_sum(irr); celm = wave_sum(celm); cell = wave_sum(cell);
  cor = wave_sum(cor);
  __shared__ float red[9][16];
  int wv = tid >> 6;
  if ((tid & 63) == 0) {
    red[0][wv] = dm; red[1][wv] = dl; red[2][wv] = ss; red[3][wv] = sel;
    red[4][wv] = ssel; red[5][wv] = irr; red[6][wv] = celm; red[7][wv] = cell;
    red[8][wv] = cor;
  }
  __syncthreads();
  if (tid == 0) {
    float a[9];
#pragma unroll
    for (int j = 0; j < 9; ++j) {
      float s = 0.f;
      for (int i = 0; i < 16; ++i) s += red[j][i];
      a[j] = s;
    }
    float pred = (iter_p[0] > 20000) ? (a[4] / fmaxf(a[3], 1.f)) : (a[2] / 2097152.f);
    out[0] = pred;
    out[1] = a[8] / 2097152.f + a[5];
    out[2] = a[7] / 131072.f + a[1] / 512.f;   // loss_low
    out[3] = a[6] / 524288.f + a[0] / 512.f;   // loss_middle
  }
}

extern "C" void kernel_launch(void* const* d_in, const int* in_sizes, int n_in,
                              void* d_out, int out_size, void* d_ws, size_t ws_size,
                              hipStream_t stream) {
  (void)in_sizes; (void)n_in; (void)out_size; (void)ws_size;
  const float* masks  = (const float*)d_in[0];
  const float* bf     = (const float*)d_in[1];
  const float* seq    = (const float*)d_in[2];
  const float* cmid   = (const float*)d_in[3];
  const float* clow   = (const float*)d_in[4];
  const int*   length = (const int*)d_in[5];
  const int*   iter   = (const int*)d_in[6];
  const float* alpha  = (const float*)d_in[7];
  float* out = (float*)d_out;

  char* ws = (char*)d_ws;
  // all scratch fully rewritten every launch -> no memset
  float* seg_part   = (float*)(ws + 0);        // 2048 f32
  float* cor_part   = (float*)(ws + 8192);     // 2048 f32
  float* irr_part   = (float*)(ws + 16384);    // 512 f32
  float* celm_part  = (float*)(ws + 18432);    // 1024 f32
  float* cell_part  = (float*)(ws + 22528);    // 512 f32
  float* inter_midP = (float*)(ws + 24576);    // 1024*26 f32 = 106496 B
  float* m1s_midP   = (float*)(ws + 131072);
  float* m2s_midP   = (float*)(ws + 237568);
  ull*          amid = (ull*)(ws + 344064);          // 512*26 u64
  unsigned int* alow = (unsigned int*)(ws + 450560); // 512*26 u32
  ull*          fmsk = (ull*)(ws + 503808);          // 512*64 u64
  float*        wsA  = (float*)(ws + 765952);        // 512*128 f32 (dead after phase2)
  // low dice arrays alias wsA region (written in k_chars after wsA's last read)
  float* inter_low = (float*)(ws + 765952);
  float* m1s_low   = (float*)(ws + 819200);
  float* m2s_low   = (float*)(ws + 872448);          // ends 925696

  k_phase1<<<NB, 128, 0, stream>>>(seq, length, alpha, wsA, amid, alow, irr_part);
  k_phase2<<<NB * 4, 256, 0, stream>>>(masks, bf, wsA, seg_part, cor_part, fmsk);

  float* out_mask = out + 4;
  float* out_smid = out + 4 + 3538944;
  float* out_slow = out + 4 + 3538944 + 13631488;

  k_chars<<<256 + 2 * NB, 512, 0, stream>>>(cmid, clow, fmsk, amid, alow,
                                            out_mask, out_smid, out_slow,
                                            celm_part, cell_part,
                                            inter_midP, m1s_midP, m2s_midP,
                                            inter_low, m1s_low, m2s_low);
  k_final<<<1, 1024, 0, stream>>>(seg_part, cor_part, irr_part, celm_part, cell_part,
                                  inter_midP, m1s_midP, m2s_midP,
                                  inter_low, m1s_low, m2s_low, length, iter, out);
}